// Round 1
// baseline (1204.372 us; speedup 1.0000x reference)
//
#include <hip/hip_runtime.h>
#include <stdint.h>

#define N_NODES 100000
#define N_EDGES 1000000
#define DIM 256   // D == H == 256

// ---------------- workspace layout (bytes) ----------------
// deg     : N u32      @ 0
// cursor  : N u32      @ 400000
// counter : 1 u32      @ 800000
// dinv    : N f32      @ 800256
// start   : N u32      @ 1200384
// col     : E i32      @ 1600512
// agg     : N*256 f32  @ 5600768
// z1      : N*256 f32  @ 108000768
// total ~ 210.4 MB

__global__ void k_zero(uint32_t* __restrict__ p, int n) {
    int i = blockIdx.x * blockDim.x + threadIdx.x;
    int stride = gridDim.x * blockDim.x;
    for (; i < n; i += stride) p[i] = 0u;
}

// count in-degrees (dst side); defensive bounds check so bad dtype shows as
// absmax error, not a memory fault
__global__ void k_count(const int* __restrict__ dst, uint32_t* __restrict__ deg) {
    int e = blockIdx.x * blockDim.x + threadIdx.x;
    if (e < N_EDGES) {
        unsigned d = (unsigned)dst[e];
        if (d < N_NODES) atomicAdd(&deg[d], 1u);
    }
}

// dinv[n] = rsqrt(deg+1); start[n] = exclusive segment offset.
// Wave-level inclusive scan + one atomic per wave (segments land in arbitrary
// order, which is fine — each node only needs its own contiguous chunk).
__global__ void k_dinv_start(const uint32_t* __restrict__ deg,
                             float* __restrict__ dinv,
                             uint32_t* __restrict__ start,
                             uint32_t* __restrict__ counter) {
    int n = blockIdx.x * blockDim.x + threadIdx.x;
    int lane = threadIdx.x & 63;
    int d = (n < N_NODES) ? (int)deg[n] : 0;
    int v = d;
    #pragma unroll
    for (int off = 1; off < 64; off <<= 1) {
        int t = __shfl_up(v, off, 64);
        if (lane >= off) v += t;
    }
    int total = __shfl(v, 63, 64);
    int base = 0;
    if (lane == 63) base = (int)atomicAdd(counter, (uint32_t)total);
    base = __shfl(base, 63, 64);
    if (n < N_NODES) {
        start[n] = (uint32_t)(base + v - d);   // exclusive
        dinv[n]  = rsqrtf((float)(d + 1));     // +1 self-loop
    }
}

__global__ void k_fill(const int* __restrict__ src, const int* __restrict__ dst,
                       const uint32_t* __restrict__ start,
                       uint32_t* __restrict__ cursor, int* __restrict__ col) {
    int e = blockIdx.x * blockDim.x + threadIdx.x;
    if (e < N_EDGES) {
        unsigned d = (unsigned)dst[e];
        unsigned s = (unsigned)src[e];
        if (d < N_NODES && s < N_NODES) {
            uint32_t p = atomicAdd(&cursor[d], 1u);
            col[start[d] + p] = (int)s;
        }
    }
}

// out[i] = dinv[i] * ( dinv[i]*rows[i] + sum_{s in N(i)} dinv[s]*rows[s] )
// one wave per node; lane handles 4 channels (float4 = 16 B/lane, 1 KB/wave)
__global__ __launch_bounds__(256) void k_gather(
        const float* __restrict__ rows, const float* __restrict__ dinv,
        const uint32_t* __restrict__ start, const uint32_t* __restrict__ deg,
        const int* __restrict__ col, float* __restrict__ out) {
    int wave = threadIdx.x >> 6;
    int lane = threadIdx.x & 63;
    int node = blockIdx.x * 4 + wave;   // grid = N/4 exactly

    const float4* r4 = (const float4*)rows;
    float di = dinv[node];
    float4 a = r4[node * 64 + lane];
    float4 acc;
    acc.x = di * a.x; acc.y = di * a.y; acc.z = di * a.z; acc.w = di * a.w;

    uint32_t s0 = start[node];
    uint32_t dg = deg[node];
    for (uint32_t j = 0; j < dg; ++j) {
        int s = col[s0 + j];
        float f = dinv[s];
        float4 b = r4[s * 64 + lane];
        acc.x += f * b.x; acc.y += f * b.y; acc.z += f * b.z; acc.w += f * b.w;
    }
    float4 o;
    o.x = di * acc.x; o.y = di * acc.y; o.z = di * acc.z; o.w = di * acc.w;
    ((float4*)out)[node * 64 + lane] = o;
}

// C[32 x 256] = relu(A_tile @ W + b); thread = one column, 32 row-accs.
// A-tile staged in LDS (all-lane broadcast reads, conflict-free).
__global__ __launch_bounds__(256) void k_gemm_relu(
        const float* __restrict__ A, const float* __restrict__ W,
        const float* __restrict__ bias, float* __restrict__ C) {
    __shared__ float As[32 * 256];   // 32 KB
    int tid = threadIdx.x;
    int rowBase = blockIdx.x * 32;   // grid = N/32 exactly

    const float4* Ab4 = (const float4*)(A + (size_t)rowBase * 256);
    float4* As4 = (float4*)As;
    #pragma unroll
    for (int i = 0; i < 8; ++i) As4[i * 256 + tid] = Ab4[i * 256 + tid];
    __syncthreads();

    float acc[32];
    #pragma unroll
    for (int r = 0; r < 32; ++r) acc[r] = 0.f;

    int c = tid;
    for (int k = 0; k < 256; k += 4) {
        float w0 = W[(k + 0) * 256 + c];
        float w1 = W[(k + 1) * 256 + c];
        float w2 = W[(k + 2) * 256 + c];
        float w3 = W[(k + 3) * 256 + c];
        #pragma unroll
        for (int r = 0; r < 32; ++r) {
            float4 a = *(const float4*)&As[r * 256 + k];
            acc[r] += a.x * w0 + a.y * w1 + a.z * w2 + a.w * w3;
        }
    }

    float b = bias[c];
    float* Cb = C + (size_t)rowBase * 256;
    #pragma unroll
    for (int r = 0; r < 32; ++r)
        Cb[r * 256 + c] = fmaxf(acc[r] + b, 0.f);
}

extern "C" void kernel_launch(void* const* d_in, const int* in_sizes, int n_in,
                              void* d_out, int out_size, void* d_ws, size_t ws_size,
                              hipStream_t stream) {
    const int*   edge = (const int*)d_in[0];   // [2][E]: row0 = src, row1 = dst
    const float* x    = (const float*)d_in[1];
    const float* W1   = (const float*)d_in[2];
    const float* b1   = (const float*)d_in[3];
    const float* W2   = (const float*)d_in[4];
    const float* b2   = (const float*)d_in[5];
    float* out = (float*)d_out;

    char* ws = (char*)d_ws;
    uint32_t* deg     = (uint32_t*)(ws + 0);
    uint32_t* cursor  = (uint32_t*)(ws + 400000);
    uint32_t* counter = (uint32_t*)(ws + 800000);
    float*    dinv    = (float*)   (ws + 800256);
    uint32_t* start   = (uint32_t*)(ws + 1200384);
    int*      col     = (int*)     (ws + 1600512);
    float*    agg     = (float*)   (ws + 5600768);
    float*    z1      = (float*)   (ws + 108000768ull);

    const int* src = edge;
    const int* dst = edge + N_EDGES;

    // ws is poisoned to 0xAA before every launch — zero deg/cursor/counter
    k_zero<<<256, 256, 0, stream>>>((uint32_t*)ws, 2 * N_NODES + 1);
    k_count<<<(N_EDGES + 255) / 256, 256, 0, stream>>>(dst, deg);
    k_dinv_start<<<(N_NODES + 255) / 256, 256, 0, stream>>>(deg, dinv, start, counter);
    k_fill<<<(N_EDGES + 255) / 256, 256, 0, stream>>>(src, dst, start, cursor, col);

    // layer 1: aggregate x, then GEMM(+bias+relu) -> z1
    k_gather<<<N_NODES / 4, 256, 0, stream>>>(x, dinv, start, deg, col, agg);
    k_gemm_relu<<<N_NODES / 32, 256, 0, stream>>>(agg, W1, b1, z1);

    // layer 2: aggregate z1, then GEMM(+bias+relu) -> out
    k_gather<<<N_NODES / 4, 256, 0, stream>>>(z1, dinv, start, deg, col, agg);
    k_gemm_relu<<<N_NODES / 32, 256, 0, stream>>>(agg, W2, b2, out);
}

// Round 2
// 685.999 us; speedup vs baseline: 1.7556x; 1.7556x over previous
//
#include <hip/hip_runtime.h>
#include <stdint.h>

#define N_NODES 100000
#define N_EDGES 1000000
#define DIM 256

typedef __attribute__((ext_vector_type(8))) short short8;   // bf16 A/B frag (4 VGPR)
typedef __attribute__((ext_vector_type(4))) float f32x4;    // fp32 C/D frag

__device__ inline float b2f(unsigned short u) {
    union { unsigned int i; float f; } v; v.i = ((unsigned int)u) << 16; return v.f;
}
__device__ inline unsigned short f2b(float f) {   // round-to-nearest-even
    union { float f; unsigned int i; } v; v.f = f;
    unsigned int u = v.i;
    return (unsigned short)((u + 0x7FFFu + ((u >> 16) & 1u)) >> 16);
}

// ---------------- workspace layout (bytes) ----------------
// deg     u32 N        @ 0
// cursor  u32 N        @ 400000
// counter u32 1        @ 800000
// dinv    f32 N        @ 800256
// start   u32 N        @ 1200384
// col     i32 E        @ 1600512
// Wt1     bf16 256x256 @ 5600512   (n-major, k contiguous)
// Wt2     bf16 256x256 @ 5731584
// xb      bf16 N*256   @ 5862656
// agg     bf16 N*256   @ 57062656
// z1      bf16 N*256   @ 108262656  (end ~159.5 MB)

__global__ void k_zero(uint32_t* __restrict__ p, int n) {
    int i = blockIdx.x * blockDim.x + threadIdx.x;
    int stride = gridDim.x * blockDim.x;
    for (; i < n; i += stride) p[i] = 0u;
}

__global__ void k_count(const int* __restrict__ dst, uint32_t* __restrict__ deg) {
    int e = blockIdx.x * blockDim.x + threadIdx.x;
    if (e < N_EDGES) {
        unsigned d = (unsigned)dst[e];
        if (d < N_NODES) atomicAdd(&deg[d], 1u);
    }
}

__global__ void k_dinv_start(const uint32_t* __restrict__ deg,
                             float* __restrict__ dinv,
                             uint32_t* __restrict__ start,
                             uint32_t* __restrict__ counter) {
    int n = blockIdx.x * blockDim.x + threadIdx.x;
    int lane = threadIdx.x & 63;
    int d = (n < N_NODES) ? (int)deg[n] : 0;
    int v = d;
    #pragma unroll
    for (int off = 1; off < 64; off <<= 1) {
        int t = __shfl_up(v, off, 64);
        if (lane >= off) v += t;
    }
    int total = __shfl(v, 63, 64);
    int base = 0;
    if (lane == 63) base = (int)atomicAdd(counter, (uint32_t)total);
    base = __shfl(base, 63, 64);
    if (n < N_NODES) {
        start[n] = (uint32_t)(base + v - d);   // exclusive
        dinv[n]  = rsqrtf((float)(d + 1));     // +1 self-loop
    }
}

__global__ void k_fill(const int* __restrict__ src, const int* __restrict__ dst,
                       const uint32_t* __restrict__ start,
                       uint32_t* __restrict__ cursor, int* __restrict__ col) {
    int e = blockIdx.x * blockDim.x + threadIdx.x;
    if (e < N_EDGES) {
        unsigned d = (unsigned)dst[e];
        unsigned s = (unsigned)src[e];
        if (d < N_NODES && s < N_NODES) {
            uint32_t p = atomicAdd(&cursor[d], 1u);
            col[start[d] + p] = (int)s;
        }
    }
}

// W (k-major, [k][n] fp32) -> Wt (n-major, [n][k] bf16)
__global__ void k_pack_w(const float* __restrict__ W, unsigned short* __restrict__ Wt) {
    int n = blockIdx.x, k = threadIdx.x;
    Wt[n * 256 + k] = f2b(W[k * 256 + n]);
}

// x fp32 -> xb bf16 (4 elems/thread)
__global__ void k_cvt_x(const float* __restrict__ x, unsigned short* __restrict__ xb) {
    int i = blockIdx.x * 256 + threadIdx.x;
    float4 v = ((const float4*)x)[i];
    ushort4 o; o.x = f2b(v.x); o.y = f2b(v.y); o.z = f2b(v.z); o.w = f2b(v.w);
    ((ushort4*)xb)[i] = o;
}

// agg[i] = dinv[i]*(dinv[i]*rows[i] + sum_s dinv[s]*rows[s]); bf16 in/out,
// fp32 accumulate. One wave/node, lane = 4 channels (ushort4 = 8 B/lane).
__global__ __launch_bounds__(256) void k_gather(
        const unsigned short* __restrict__ rows, const float* __restrict__ dinv,
        const uint32_t* __restrict__ start, const uint32_t* __restrict__ deg,
        const int* __restrict__ col, unsigned short* __restrict__ out) {
    int wave = threadIdx.x >> 6;
    int lane = threadIdx.x & 63;
    int node = blockIdx.x * 4 + wave;   // grid = N/4 exactly

    const ushort4* r4 = (const ushort4*)rows;
    float di = dinv[node];
    ushort4 a = r4[node * 64 + lane];
    float ax = di * b2f(a.x), ay = di * b2f(a.y), az = di * b2f(a.z), aw = di * b2f(a.w);

    uint32_t s0 = start[node];
    uint32_t dg = deg[node];
    for (uint32_t j = 0; j < dg; ++j) {
        int s = col[s0 + j];
        float f = dinv[s];
        ushort4 b = r4[s * 64 + lane];
        ax += f * b2f(b.x); ay += f * b2f(b.y); az += f * b2f(b.z); aw += f * b2f(b.w);
    }
    ushort4 o;
    o.x = f2b(di * ax); o.y = f2b(di * ay); o.z = f2b(di * az); o.w = f2b(di * aw);
    ((ushort4*)out)[node * 64 + lane] = o;
}

// C[64 x 256] = relu(A_tile @ W + b). 4 waves; wave w -> cols [64w,64w+64).
// A (bf16) staged once in LDS full-K, row stride 264 ush (528 B, 2-way-free banks).
// B frags loaded straight from packed global Wt[n][k] (L1/L2 resident).
// Cb!=null -> bf16 store (z1); else fp32 store to Cf.
__global__ __launch_bounds__(256) void k_gemm(
        const unsigned short* __restrict__ A, const unsigned short* __restrict__ Wt,
        const float* __restrict__ bias,
        unsigned short* __restrict__ Cb, float* __restrict__ Cf) {
    __shared__ unsigned short As[64 * 264];   // 33792 B
    int tid = threadIdx.x;
    int wave = tid >> 6, lane = tid & 63;
    int rowBase = blockIdx.x * 64;

    // stage A: 64 rows x 512 B = 2048 x 16B chunks; thread t -> chunks t+256i
    #pragma unroll
    for (int i = 0; i < 8; ++i) {
        int c  = tid + i * 256;
        int r  = c >> 5;           // 32 x 16B per row
        int kb = c & 31;
        int gr = rowBase + r;
        int4 v;
        if (gr < N_NODES) v = *(const int4*)(A + (size_t)gr * 256 + kb * 8);
        else              { v.x = 0; v.y = 0; v.z = 0; v.w = 0; }
        *(int4*)((char*)As + r * 528 + kb * 16) = v;
    }
    __syncthreads();

    int quad = lane >> 4;
    int m    = lane & 15;
    int nCol = wave * 64 + (lane & 15);

    f32x4 acc[4][4];
    #pragma unroll
    for (int mt = 0; mt < 4; ++mt)
        #pragma unroll
        for (int nt = 0; nt < 4; ++nt)
            acc[mt][nt] = (f32x4){0.f, 0.f, 0.f, 0.f};

    #pragma unroll
    for (int ks = 0; ks < 8; ++ks) {          // K = 8 steps x 32
        short8 bfrag[4];
        #pragma unroll
        for (int nt = 0; nt < 4; ++nt)
            bfrag[nt] = *(const short8*)(Wt + (size_t)(nCol + nt * 16) * 256 + ks * 32 + quad * 8);
        short8 afrag[4];
        #pragma unroll
        for (int mt = 0; mt < 4; ++mt)
            afrag[mt] = *(const short8*)((char*)As + (mt * 16 + m) * 528 + ks * 64 + quad * 16);
        #pragma unroll
        for (int mt = 0; mt < 4; ++mt)
            #pragma unroll
            for (int nt = 0; nt < 4; ++nt)
                acc[mt][nt] = __builtin_amdgcn_mfma_f32_16x16x32_bf16(
                    afrag[mt], bfrag[nt], acc[mt][nt], 0, 0, 0);
    }

    // epilogue: C/D layout col=lane&15, row=quad*4+reg
    #pragma unroll
    for (int nt = 0; nt < 4; ++nt) {
        int c = wave * 64 + nt * 16 + (lane & 15);
        float bv = bias[c];
        #pragma unroll
        for (int mt = 0; mt < 4; ++mt) {
            #pragma unroll
            for (int r = 0; r < 4; ++r) {
                int row = rowBase + mt * 16 + quad * 4 + r;
                if (row < N_NODES) {
                    float v = fmaxf(acc[mt][nt][r] + bv, 0.f);
                    if (Cf) Cf[(size_t)row * 256 + c] = v;
                    else    Cb[(size_t)row * 256 + c] = f2b(v);
                }
            }
        }
    }
}

extern "C" void kernel_launch(void* const* d_in, const int* in_sizes, int n_in,
                              void* d_out, int out_size, void* d_ws, size_t ws_size,
                              hipStream_t stream) {
    const int*   edge = (const int*)d_in[0];   // [2][E]: row0 = src, row1 = dst
    const float* x    = (const float*)d_in[1];
    const float* W1   = (const float*)d_in[2];
    const float* b1   = (const float*)d_in[3];
    const float* W2   = (const float*)d_in[4];
    const float* b2   = (const float*)d_in[5];
    float* out = (float*)d_out;

    char* ws = (char*)d_ws;
    uint32_t*       deg     = (uint32_t*)(ws + 0);
    uint32_t*       cursor  = (uint32_t*)(ws + 400000);
    uint32_t*       counter = (uint32_t*)(ws + 800000);
    float*          dinv    = (float*)   (ws + 800256);
    uint32_t*       start   = (uint32_t*)(ws + 1200384);
    int*            col     = (int*)     (ws + 1600512);
    unsigned short* Wt1     = (unsigned short*)(ws + 5600512);
    unsigned short* Wt2     = (unsigned short*)(ws + 5731584);
    unsigned short* xb      = (unsigned short*)(ws + 5862656);
    unsigned short* agg     = (unsigned short*)(ws + 57062656ull);
    unsigned short* z1      = (unsigned short*)(ws + 108262656ull);

    const int* src = edge;
    const int* dst = edge + N_EDGES;

    k_zero<<<256, 256, 0, stream>>>((uint32_t*)ws, 2 * N_NODES + 1);
    k_count<<<(N_EDGES + 255) / 256, 256, 0, stream>>>(dst, deg);
    k_dinv_start<<<(N_NODES + 255) / 256, 256, 0, stream>>>(deg, dinv, start, counter);
    k_fill<<<(N_EDGES + 255) / 256, 256, 0, stream>>>(src, dst, start, cursor, col);

    k_pack_w<<<256, 256, 0, stream>>>(W1, Wt1);
    k_pack_w<<<256, 256, 0, stream>>>(W2, Wt2);
    k_cvt_x<<<(N_NODES * DIM / 4) / 256, 256, 0, stream>>>(x, xb);

    // layer 1
    k_gather<<<N_NODES / 4, 256, 0, stream>>>(xb, dinv, start, deg, col, agg);
    k_gemm<<<(N_NODES + 63) / 64, 256, 0, stream>>>(agg, Wt1, b1, z1, nullptr);
    // layer 2
    k_gather<<<N_NODES / 4, 256, 0, stream>>>(z1, dinv, start, deg, col, agg);
    k_gemm<<<(N_NODES + 63) / 64, 256, 0, stream>>>(agg, Wt2, b2, nullptr, out);
}

// Round 3
// 616.569 us; speedup vs baseline: 1.9533x; 1.1126x over previous
//
#include <hip/hip_runtime.h>
#include <stdint.h>

#define N_NODES 100000
#define N_EDGES 1000000
#define DIM 256

typedef __attribute__((ext_vector_type(8))) short short8;   // bf16 A/B frag (4 VGPR)
typedef __attribute__((ext_vector_type(4))) float f32x4;    // fp32 C/D frag

__device__ inline float b2f(unsigned short u) {
    union { unsigned int i; float f; } v; v.i = ((unsigned int)u) << 16; return v.f;
}
__device__ inline unsigned short f2b(float f) {   // round-to-nearest-even
    union { float f; unsigned int i; } v; v.f = f;
    unsigned int u = v.i;
    return (unsigned short)((u + 0x7FFFu + ((u >> 16) & 1u)) >> 16);
}

// ---------------- workspace layout (bytes) ----------------
// deg     u32 N        @ 0
// cursor  u32 N        @ 400000
// counter u32 1        @ 800000
// dinv    f32 N        @ 800256
// start   u32 N        @ 1200384
// col     i32 E        @ 1600512
// Wt1     bf16 256x256 @ 5600512   (n-major, k contiguous)
// Wt2     bf16 256x256 @ 5731584
// xs      bf16 N*256   @ 5862656    (dinv-prescaled features, layer input)
// agg     bf16 N*256   @ 57062656
// z1s     bf16 N*256   @ 108262656  (dinv-prescaled layer-1 output)

__global__ void k_zero(uint32_t* __restrict__ p, int n) {
    int i = blockIdx.x * blockDim.x + threadIdx.x;
    int stride = gridDim.x * blockDim.x;
    for (; i < n; i += stride) p[i] = 0u;
}

__global__ void k_count(const int* __restrict__ dst, uint32_t* __restrict__ deg) {
    int e = blockIdx.x * blockDim.x + threadIdx.x;
    if (e < N_EDGES) {
        unsigned d = (unsigned)dst[e];
        if (d < N_NODES) atomicAdd(&deg[d], 1u);
    }
}

__global__ void k_dinv_start(const uint32_t* __restrict__ deg,
                             float* __restrict__ dinv,
                             uint32_t* __restrict__ start,
                             uint32_t* __restrict__ counter) {
    int n = blockIdx.x * blockDim.x + threadIdx.x;
    int lane = threadIdx.x & 63;
    int d = (n < N_NODES) ? (int)deg[n] : 0;
    int v = d;
    #pragma unroll
    for (int off = 1; off < 64; off <<= 1) {
        int t = __shfl_up(v, off, 64);
        if (lane >= off) v += t;
    }
    int total = __shfl(v, 63, 64);
    int base = 0;
    if (lane == 63) base = (int)atomicAdd(counter, (uint32_t)total);
    base = __shfl(base, 63, 64);
    if (n < N_NODES) {
        start[n] = (uint32_t)(base + v - d);   // exclusive
        dinv[n]  = rsqrtf((float)(d + 1));     // +1 self-loop
    }
}

__global__ void k_fill(const int* __restrict__ src, const int* __restrict__ dst,
                       const uint32_t* __restrict__ start,
                       uint32_t* __restrict__ cursor, int* __restrict__ col) {
    int e = blockIdx.x * blockDim.x + threadIdx.x;
    if (e < N_EDGES) {
        unsigned d = (unsigned)dst[e];
        unsigned s = (unsigned)src[e];
        if (d < N_NODES && s < N_NODES) {
            uint32_t p = atomicAdd(&cursor[d], 1u);
            col[start[d] + p] = (int)s;
        }
    }
}

// W (k-major, [k][n] fp32) -> Wt (n-major, [n][k] bf16)
__global__ void k_pack_w(const float* __restrict__ W, unsigned short* __restrict__ Wt) {
    int n = blockIdx.x, k = threadIdx.x;
    Wt[n * 256 + k] = f2b(W[k * 256 + n]);
}

// xs[row] = bf16( dinv[row] * x[row] )  (4 elems/thread; 16 threads/row)
__global__ void k_cvt_x(const float* __restrict__ x, const float* __restrict__ dinv,
                        unsigned short* __restrict__ xs) {
    int i = blockIdx.x * 256 + threadIdx.x;   // float4 index
    int row = i >> 6;                          // 64 float4 per row
    float di = dinv[row];
    float4 v = ((const float4*)x)[i];
    ushort4 o;
    o.x = f2b(di * v.x); o.y = f2b(di * v.y); o.z = f2b(di * v.z); o.w = f2b(di * v.w);
    ((ushort4*)xs)[i] = o;
}

// agg[i] = bf16( dinv[i] * ( xs[i] + sum_{s in N(i)} xs[s] ) )
// rows are dinv-prescaled, so the inner loop is a pure row-sum:
// one index load + one independent 8 B/lane row load per edge, unrolled x4
// for 4 outstanding 512 B row fetches per wave (MLP).
__global__ __launch_bounds__(256) void k_gather(
        const unsigned short* __restrict__ rows, const float* __restrict__ dinv,
        const uint32_t* __restrict__ start, const uint32_t* __restrict__ deg,
        const int* __restrict__ col, unsigned short* __restrict__ out) {
    int wave = threadIdx.x >> 6;
    int lane = threadIdx.x & 63;
    int node = blockIdx.x * 4 + wave;   // grid = N/4 exactly

    const ushort4* r4 = (const ushort4*)rows;
    float di = dinv[node];
    ushort4 a = r4[node * 64 + lane];   // self term (already prescaled)
    float ax = b2f(a.x), ay = b2f(a.y), az = b2f(a.z), aw = b2f(a.w);

    uint32_t s0 = start[node];
    uint32_t dg = deg[node];
    uint32_t j = 0;
    for (; j + 4 <= dg; j += 4) {
        int i0 = col[s0 + j + 0];
        int i1 = col[s0 + j + 1];
        int i2 = col[s0 + j + 2];
        int i3 = col[s0 + j + 3];
        ushort4 b0 = r4[i0 * 64 + lane];
        ushort4 b1 = r4[i1 * 64 + lane];
        ushort4 b2 = r4[i2 * 64 + lane];
        ushort4 b3 = r4[i3 * 64 + lane];
        ax += b2f(b0.x) + b2f(b1.x) + b2f(b2.x) + b2f(b3.x);
        ay += b2f(b0.y) + b2f(b1.y) + b2f(b2.y) + b2f(b3.y);
        az += b2f(b0.z) + b2f(b1.z) + b2f(b2.z) + b2f(b3.z);
        aw += b2f(b0.w) + b2f(b1.w) + b2f(b2.w) + b2f(b3.w);
    }
    for (; j < dg; ++j) {
        int s = col[s0 + j];
        ushort4 b = r4[s * 64 + lane];
        ax += b2f(b.x); ay += b2f(b.y); az += b2f(b.z); aw += b2f(b.w);
    }
    ushort4 o;
    o.x = f2b(di * ax); o.y = f2b(di * ay); o.z = f2b(di * az); o.w = f2b(di * aw);
    ((ushort4*)out)[node * 64 + lane] = o;
}

// C[64 x 256] = relu(A_tile @ W + b). 4 waves; wave w -> cols [64w,64w+64).
// A (bf16) staged once in LDS full-K, row stride 264 ush (528 B).
// B frags loaded from packed global Wt[n][k] (L1/L2 resident).
// Cb!=null -> bf16 store of dinv[row]*relu(...) (prescaled layer-2 input);
// else fp32 relu(...) to Cf (final output).
__global__ __launch_bounds__(256) void k_gemm(
        const unsigned short* __restrict__ A, const unsigned short* __restrict__ Wt,
        const float* __restrict__ bias, const float* __restrict__ dinv,
        unsigned short* __restrict__ Cb, float* __restrict__ Cf) {
    __shared__ unsigned short As[64 * 264];   // 33792 B
    int tid = threadIdx.x;
    int wave = tid >> 6, lane = tid & 63;
    int rowBase = blockIdx.x * 64;

    // stage A: 64 rows x 512 B = 2048 x 16B chunks; thread t -> chunks t+256i
    #pragma unroll
    for (int i = 0; i < 8; ++i) {
        int c  = tid + i * 256;
        int r  = c >> 5;           // 32 x 16B per row
        int kb = c & 31;
        int gr = rowBase + r;
        int4 v;
        if (gr < N_NODES) v = *(const int4*)(A + (size_t)gr * 256 + kb * 8);
        else              { v.x = 0; v.y = 0; v.z = 0; v.w = 0; }
        *(int4*)((char*)As + r * 528 + kb * 16) = v;
    }
    __syncthreads();

    int quad = lane >> 4;
    int m    = lane & 15;
    int nCol = wave * 64 + (lane & 15);

    f32x4 acc[4][4];
    #pragma unroll
    for (int mt = 0; mt < 4; ++mt)
        #pragma unroll
        for (int nt = 0; nt < 4; ++nt)
            acc[mt][nt] = (f32x4){0.f, 0.f, 0.f, 0.f};

    #pragma unroll
    for (int ks = 0; ks < 8; ++ks) {          // K = 8 steps x 32
        short8 bfrag[4];
        #pragma unroll
        for (int nt = 0; nt < 4; ++nt)
            bfrag[nt] = *(const short8*)(Wt + (size_t)(nCol + nt * 16) * 256 + ks * 32 + quad * 8);
        short8 afrag[4];
        #pragma unroll
        for (int mt = 0; mt < 4; ++mt)
            afrag[mt] = *(const short8*)((char*)As + (mt * 16 + m) * 528 + ks * 64 + quad * 16);
        #pragma unroll
        for (int mt = 0; mt < 4; ++mt)
            #pragma unroll
            for (int nt = 0; nt < 4; ++nt)
                acc[mt][nt] = __builtin_amdgcn_mfma_f32_16x16x32_bf16(
                    afrag[mt], bfrag[nt], acc[mt][nt], 0, 0, 0);
    }

    // epilogue: C/D layout col=lane&15, row=quad*4+reg
    #pragma unroll
    for (int nt = 0; nt < 4; ++nt) {
        int c = wave * 64 + nt * 16 + (lane & 15);
        float bv = bias[c];
        #pragma unroll
        for (int mt = 0; mt < 4; ++mt) {
            #pragma unroll
            for (int r = 0; r < 4; ++r) {
                int row = rowBase + mt * 16 + quad * 4 + r;
                if (row < N_NODES) {
                    float v = fmaxf(acc[mt][nt][r] + bv, 0.f);
                    if (Cf) Cf[(size_t)row * 256 + c] = v;
                    else    Cb[(size_t)row * 256 + c] = f2b(dinv[row] * v);
                }
            }
        }
    }
}

extern "C" void kernel_launch(void* const* d_in, const int* in_sizes, int n_in,
                              void* d_out, int out_size, void* d_ws, size_t ws_size,
                              hipStream_t stream) {
    const int*   edge = (const int*)d_in[0];   // [2][E]: row0 = src, row1 = dst
    const float* x    = (const float*)d_in[1];
    const float* W1   = (const float*)d_in[2];
    const float* b1   = (const float*)d_in[3];
    const float* W2   = (const float*)d_in[4];
    const float* b2   = (const float*)d_in[5];
    float* out = (float*)d_out;

    char* ws = (char*)d_ws;
    uint32_t*       deg     = (uint32_t*)(ws + 0);
    uint32_t*       cursor  = (uint32_t*)(ws + 400000);
    uint32_t*       counter = (uint32_t*)(ws + 800000);
    float*          dinv    = (float*)   (ws + 800256);
    uint32_t*       start   = (uint32_t*)(ws + 1200384);
    int*            col     = (int*)     (ws + 1600512);
    unsigned short* Wt1     = (unsigned short*)(ws + 5600512);
    unsigned short* Wt2     = (unsigned short*)(ws + 5731584);
    unsigned short* xs      = (unsigned short*)(ws + 5862656);
    unsigned short* agg     = (unsigned short*)(ws + 57062656ull);
    unsigned short* z1s     = (unsigned short*)(ws + 108262656ull);

    const int* src = edge;
    const int* dst = edge + N_EDGES;

    k_zero<<<256, 256, 0, stream>>>((uint32_t*)ws, 2 * N_NODES + 1);
    k_count<<<(N_EDGES + 255) / 256, 256, 0, stream>>>(dst, deg);
    k_dinv_start<<<(N_NODES + 255) / 256, 256, 0, stream>>>(deg, dinv, start, counter);
    k_fill<<<(N_EDGES + 255) / 256, 256, 0, stream>>>(src, dst, start, cursor, col);

    k_pack_w<<<256, 256, 0, stream>>>(W1, Wt1);
    k_pack_w<<<256, 256, 0, stream>>>(W2, Wt2);
    k_cvt_x<<<(N_NODES * DIM / 4) / 256, 256, 0, stream>>>(x, dinv, xs);

    // layer 1 (gemm epilogue writes dinv-prescaled z1s)
    k_gather<<<N_NODES / 4, 256, 0, stream>>>(xs, dinv, start, deg, col, agg);
    k_gemm<<<(N_NODES + 63) / 64, 256, 0, stream>>>(agg, Wt1, b1, dinv, z1s, nullptr);
    // layer 2
    k_gather<<<N_NODES / 4, 256, 0, stream>>>(z1s, dinv, start, deg, col, agg);
    k_gemm<<<(N_NODES + 63) / 64, 256, 0, stream>>>(agg, Wt2, b2, dinv, nullptr, out);
}